// Round 1
// 461.754 us; speedup vs baseline: 1.0067x; 1.0067x over previous
//
#include <hip/hip_runtime.h>

// ---------------- static problem configuration ----------------
#define E      32768
#define F      64
#define G      64
#define B      2
#define L      3
#define H      256
#define P      8              // B^L
#define D      4              // L+1
#define N0     (15*E)         // 491520 existing node rows
#define OFF3   (7*E)          // first row of level-3 nodes
#define NROWS  (P*E)          // 262144 parent rows to run the MLP on
#define BE     (B*E)          // 65536
#define EC0    1114112        // existing edge count
#define ECN    (P*D*BE)       // 2097152 new edges
#define EC1    (EC0 + ECN)    // 3211264
#define NEV    (N0 + P*BE)    // 1015808

// Output layout (all float32, concatenated):
#define SXN   (NEV * F)          // 65011712
#define OXE   SXN
#define OEA   (OXE + 2*EC1)      // 71434240
#define OEV   (OEA + EC1)        // 74645504

// fused grid partition
#define MLP_BLOCKS   4096                      // 64 rows each
#define COPY_BLOCKS  3840                      // 2048 float4 each -> N0*F/4
#define AUX_BLOCKS   784                       // 4 x 200704 i4-groups -> EC1/4
#define AUX_STRIDE   (AUX_BLOCKS * 256)        // 200704
#define TOT_BLOCKS   (MLP_BLOCKS + COPY_BLOCKS + AUX_BLOCKS)

using short8  = __attribute__((ext_vector_type(8))) short;
using floatx4 = __attribute__((ext_vector_type(4))) float;

__device__ __forceinline__ ushort f2b(float f) {
    unsigned u = __float_as_uint(f);
    return (ushort)((u + 0x7fffu + ((u >> 16) & 1u)) >> 16);
}

// ---------------- kernel 0: pack W1/W2 into bf16 MFMA fragment order ------
// Identical pack as before. Because A- and B-fragments of mfma_f32_16x16x32_bf16
// share the same lane->element map (16-dim on lane&15, K on quad*8+j), this
// pack serves as B-frag of W (h@W) AND as A-frag of W^T (swapped mfma).
__global__ __launch_bounds__(256) void pack_kernel(const float* __restrict__ W1,
                                                   const float* __restrict__ W2,
                                                   ushort* __restrict__ wp) {
    int t = blockIdx.x * 256 + threadIdx.x;   // 0..8191
    ushort tmp[8];
    if (t < 4096) {
        int lane = t & 63, nt = (t >> 6) & 3, kt = (t >> 8) & 3, w = (t >> 10) & 3;
        int col = w * 64 + nt * 16 + (lane & 15);
        int kb  = kt * 32 + (lane >> 4) * 8;
        #pragma unroll
        for (int j = 0; j < 8; ++j) tmp[j] = f2b(W1[(kb + j) * 256 + col]);
        uint4 v = make_uint4((unsigned)tmp[0] | ((unsigned)tmp[1] << 16),
                             (unsigned)tmp[2] | ((unsigned)tmp[3] << 16),
                             (unsigned)tmp[4] | ((unsigned)tmp[5] << 16),
                             (unsigned)tmp[6] | ((unsigned)tmp[7] << 16));
        *(uint4*)(wp + t * 8) = v;
    } else {
        int t2 = t - 4096;
        int lane = t2 & 63, nt = (t2 >> 6) & 1, kt = (t2 >> 7) & 7, w = (t2 >> 10) & 3;
        int col = w * 32 + nt * 16 + (lane & 15);
        int kb  = kt * 32 + (lane >> 4) * 8;
        #pragma unroll
        for (int j = 0; j < 8; ++j) tmp[j] = f2b(W2[(kb + j) * 128 + col]);
        uint4 v = make_uint4((unsigned)tmp[0] | ((unsigned)tmp[1] << 16),
                             (unsigned)tmp[2] | ((unsigned)tmp[3] << 16),
                             (unsigned)tmp[4] | ((unsigned)tmp[5] << 16),
                             (unsigned)tmp[6] | ((unsigned)tmp[7] << 16));
        *(uint4*)(wp + 32768 + t2 * 8) = v;
    }
}

// ---------------- fused kernel: MLP (MFMA) + x-copy + edges/attrs/events ---
// Blocks [0,4096): MLP, 64 rows/block. Blocks [4096,7936): copy. Rest: aux.
#define HP1 136   // h tile row pitch (128 + 8 pad), bf16 elems; 272 B
#define HP2 264   // hidden tile row pitch (256 + 8), 528 B
__global__ __launch_bounds__(256, 2) void fused_kernel(const float* __restrict__ x,
                                                       const float* __restrict__ gf,
                                                       const ushort* __restrict__ wpack,
                                                       const float* __restrict__ b1,
                                                       const float* __restrict__ b2,
                                                       const int* __restrict__ ei,
                                                       const int* __restrict__ ea,
                                                       const int* __restrict__ ev,
                                                       float* __restrict__ out) {
    __shared__ ushort hsh[64 * HP1];
    __shared__ ushort hid[64 * HP2];
    const int bid = blockIdx.x;
    const int tid = threadIdx.x;

    if (bid < MLP_BLOCKS) {
        const int wave = tid >> 6, lane = tid & 63;
        const int quad = lane >> 4, l16 = lane & 15;
        const int row0 = bid * 64;

        // ---- preload W1 fragments (A-frag of W1^T; same bytes as before) ----
        short8 w1f[4][4];   // [kt][nt]
        {
            const ushort* wp1 = wpack + wave * 8192;
            #pragma unroll
            for (int kt = 0; kt < 4; ++kt)
                #pragma unroll
                for (int nt = 0; nt < 4; ++nt)
                    w1f[kt][nt] = *(const short8*)(wp1 + (kt * 4 + nt) * 512 + lane * 8);
        }

        // ---- stage h = [x_row | gf[e]] as bf16: 64 rows x 128 ----
        #pragma unroll
        for (int it = 0; it < 4; ++it) {
            int q  = tid + 256 * it;      // 0..1023
            int r  = q >> 4;              // row 0..63
            int cc = q & 15;              // 8-elem chunk 0..15
            int rg = row0 + r;
            const float* src = (cc < 8) ? (x + (OFF3 + rg) * 64 + cc * 8)
                                        : (gf + (rg & (E - 1)) * 64 + (cc - 8) * 8);
            float4 a  = *(const float4*)src;
            float4 bv = *(const float4*)(src + 4);
            uint4 v = make_uint4((unsigned)f2b(a.x)  | ((unsigned)f2b(a.y)  << 16),
                                 (unsigned)f2b(a.z)  | ((unsigned)f2b(a.w)  << 16),
                                 (unsigned)f2b(bv.x) | ((unsigned)f2b(bv.y) << 16),
                                 (unsigned)f2b(bv.z) | ((unsigned)f2b(bv.w) << 16));
            *(uint4*)&hsh[r * HP1 + cc * 8] = v;
        }
        __syncthreads();

        // ---- GEMM1 (swapped): D[n][m] = W1^T x h^T. Lane holds fixed m=mt*16+l16,
        //      4 consecutive n = wave*64+nt*16+quad*4+i  -> packed b64 LDS writes.
        floatx4 acc1[4][4];   // [mt][nt]
        #pragma unroll
        for (int mt = 0; mt < 4; ++mt)
            #pragma unroll
            for (int nt = 0; nt < 4; ++nt)
                acc1[mt][nt] = (floatx4){0.f, 0.f, 0.f, 0.f};
        #pragma unroll
        for (int mt = 0; mt < 4; ++mt) {
            short8 af[4];
            #pragma unroll
            for (int kt = 0; kt < 4; ++kt)
                af[kt] = *(const short8*)&hsh[(mt * 16 + l16) * HP1 + kt * 32 + quad * 8];
            #pragma unroll
            for (int nt = 0; nt < 4; ++nt)
                #pragma unroll
                for (int kt = 0; kt < 4; ++kt)
                    acc1[mt][nt] = __builtin_amdgcn_mfma_f32_16x16x32_bf16(
                        w1f[kt][nt], af[kt], acc1[mt][nt], 0, 0, 0);
        }

        // ---- preload W2 fragments now (deferred to cut peak VGPR; latency
        //      hides under epilogue-1 LDS writes + barrier) ----
        short8 w2f[8][2];   // [kt][nt]
        {
            const ushort* wp2 = wpack + 32768 + wave * 8192;
            #pragma unroll
            for (int kt = 0; kt < 8; ++kt)
                #pragma unroll
                for (int nt = 0; nt < 2; ++nt)
                    w2f[kt][nt] = *(const short8*)(wp2 + (kt * 2 + nt) * 512 + lane * 8);
        }

        // ---- epilogue 1: bias+relu -> bf16, packed 8B LDS writes ----
        #pragma unroll
        for (int nt = 0; nt < 4; ++nt) {
            float4 bb = *(const float4*)(b1 + wave * 64 + nt * 16 + quad * 4);
            #pragma unroll
            for (int mt = 0; mt < 4; ++mt) {
                int m = mt * 16 + l16;
                unsigned lo = (unsigned)f2b(fmaxf(acc1[mt][nt][0] + bb.x, 0.f)) |
                              ((unsigned)f2b(fmaxf(acc1[mt][nt][1] + bb.y, 0.f)) << 16);
                unsigned hi = (unsigned)f2b(fmaxf(acc1[mt][nt][2] + bb.z, 0.f)) |
                              ((unsigned)f2b(fmaxf(acc1[mt][nt][3] + bb.w, 0.f)) << 16);
                uint2 v = make_uint2(lo, hi);
                *(uint2*)&hid[m * HP2 + wave * 64 + nt * 16 + quad * 4] = v;
            }
        }
        __syncthreads();

        // ---- GEMM2 (swapped): lane holds fixed m, 4 consecutive out cols ----
        floatx4 acc2[4][2];
        #pragma unroll
        for (int mt = 0; mt < 4; ++mt)
            #pragma unroll
            for (int nt = 0; nt < 2; ++nt)
                acc2[mt][nt] = (floatx4){0.f, 0.f, 0.f, 0.f};
        #pragma unroll
        for (int mt = 0; mt < 4; ++mt) {
            short8 hf[8];
            #pragma unroll
            for (int kt = 0; kt < 8; ++kt)
                hf[kt] = *(const short8*)&hid[(mt * 16 + l16) * HP2 + kt * 32 + quad * 8];
            #pragma unroll
            for (int nt = 0; nt < 2; ++nt)
                #pragma unroll
                for (int kt = 0; kt < 8; ++kt)
                    acc2[mt][nt] = __builtin_amdgcn_mfma_f32_16x16x32_bf16(
                        w2f[kt][nt], hf[kt], acc2[mt][nt], 0, 0, 0);
        }
        #pragma unroll
        for (int nt = 0; nt < 2; ++nt) {
            float4 bb = *(const float4*)(b2 + wave * 32 + nt * 16 + quad * 4);
            #pragma unroll
            for (int mt = 0; mt < 4; ++mt) {
                int m = mt * 16 + l16;
                float4 v = make_float4(acc2[mt][nt][0] + bb.x, acc2[mt][nt][1] + bb.y,
                                       acc2[mt][nt][2] + bb.z, acc2[mt][nt][3] + bb.w);
                *(float4*)(out + N0 * F + (row0 + m) * 128 + wave * 32 + nt * 16 + quad * 4) = v;
            }
        }
    } else if (bid < MLP_BLOCKS + COPY_BLOCKS) {
        // ---- copy x rows: 2048 float4 per block, 8 per thread ----
        int cb = bid - MLP_BLOCKS;
        const float4* src = (const float4*)x;
        float4* dst = (float4*)out;
        int base = cb * 2048 + tid;
        float4 v[8];
        #pragma unroll
        for (int j = 0; j < 8; ++j) v[j] = src[base + j * 256];
        #pragma unroll
        for (int j = 0; j < 8; ++j) dst[base + j * 256] = v[j];
    } else {
        // ---- edges / attrs / events (4-wide), grid-strided ----
        int ab = bid - MLP_BLOCKS - COPY_BLOCKS;
        #pragma unroll
        for (int it = 0; it < 4; ++it) {
            int i4 = ab * 256 + tid + it * AUX_STRIDE;
            if (i4 < EC1 / 4) {
                int i = i4 * 4;
                float4 sf, tf, af;
                if (i < EC0) {
                    int4 sv = ((const int4*)ei)[i4];
                    int4 tv = ((const int4*)(ei + EC0))[i4];
                    int4 av = ((const int4*)ea)[i4];
                    sf = make_float4((float)sv.x, (float)sv.y, (float)sv.z, (float)sv.w);
                    tf = make_float4((float)tv.x, (float)tv.y, (float)tv.z, (float)tv.w);
                    af = make_float4((float)av.x, (float)av.y, (float)av.z, (float)av.w);
                } else {
                    float s[4], t[4], a[4];
                    #pragma unroll
                    for (int q = 0; q < 4; ++q) {
                        int k = i + q - EC0;
                        int p = k >> 18;
                        int r = k & (262144 - 1);
                        int d = r >> 16;
                        int j = r & (BE - 1);
                        s[q] = (float)(E * (((8 >> d) - 1) + (p >> d)) + (j & (E - 1)));
                        t[q] = (float)(N0 + p * BE + j);
                        a[q] = (float)(d + 1);
                    }
                    sf = make_float4(s[0], s[1], s[2], s[3]);
                    tf = make_float4(t[0], t[1], t[2], t[3]);
                    af = make_float4(a[0], a[1], a[2], a[3]);
                }
                ((float4*)(out + OXE))[i4]       = sf;
                ((float4*)(out + OXE + EC1))[i4] = tf;
                ((float4*)(out + OEA))[i4]       = af;
            }
            if (i4 < NEV / 4) {
                int i = i4 * 4;
                float4 v;
                if (i < N0) {
                    int4 e = ((const int4*)ev)[i4];
                    v = make_float4((float)e.x, (float)e.y, (float)e.z, (float)e.w);
                } else {
                    int base = (i - N0) & (E - 1);
                    v = make_float4((float)base, (float)(base + 1), (float)(base + 2), (float)(base + 3));
                }
                ((float4*)(out + OEV))[i4] = v;
            }
        }
    }
}

// ---------------- launcher ----------------
extern "C" void kernel_launch(void* const* d_in, const int* in_sizes, int n_in,
                              void* d_out, int out_size, void* d_ws, size_t ws_size,
                              hipStream_t stream) {
    const float* x  = (const float*)d_in[0];
    const int*   ei = (const int*)d_in[1];
    const int*   ea = (const int*)d_in[2];
    const int*   ev = (const int*)d_in[3];
    const float* gf = (const float*)d_in[4];
    const float* W1 = (const float*)d_in[5];
    const float* W2 = (const float*)d_in[7];
    const float* b1 = (const float*)d_in[6];
    const float* b2 = (const float*)d_in[8];
    float* out = (float*)d_out;
    ushort* wpack = (ushort*)d_ws;   // 65536 bf16 = 128 KB

    pack_kernel<<<32, 256, 0, stream>>>(W1, W2, wpack);
    fused_kernel<<<TOT_BLOCKS, 256, 0, stream>>>(x, gf, wpack, b1, b2,
                                                 ei, ea, ev, out);
}

// Round 2
// 446.893 us; speedup vs baseline: 1.0402x; 1.0333x over previous
//
#include <hip/hip_runtime.h>

// ---------------- static problem configuration ----------------
#define E      32768
#define F      64
#define G      64
#define B      2
#define L      3
#define H      256
#define P      8              // B^L
#define D      4              // L+1
#define N0     (15*E)         // 491520 existing node rows
#define OFF3   (7*E)          // first row of level-3 nodes
#define NROWS  (P*E)          // 262144 parent rows to run the MLP on
#define BE     (B*E)          // 65536
#define EC0    1114112        // existing edge count
#define ECN    (P*D*BE)       // 2097152 new edges
#define EC1    (EC0 + ECN)    // 3211264
#define NEV    (N0 + P*BE)    // 1015808

// Output layout (all float32, concatenated):
#define SXN   (NEV * F)          // 65011712
#define OXE   SXN
#define OEA   (OXE + 2*EC1)      // 71434240
#define OEV   (OEA + EC1)        // 74645504

// fused grid partition
// MLP blocks also write through the level-3 x rows -> copy covers [0, 7E) only.
#define MLP_BLOCKS   4096                      // 64 rows each
#define COPY_BLOCKS  1792                      // 2048 float4 each -> 7E*F/4
#define AUX_BLOCKS   784                       // 4 x 200704 i4-groups -> EC1/4
#define AUX_STRIDE   (AUX_BLOCKS * 256)        // 200704
#define TOT_BLOCKS   (MLP_BLOCKS + COPY_BLOCKS + AUX_BLOCKS)

using short8  = __attribute__((ext_vector_type(8))) short;
using floatx4 = __attribute__((ext_vector_type(4))) float;

__device__ __forceinline__ ushort f2b(float f) {
    unsigned u = __float_as_uint(f);
    return (ushort)((u + 0x7fffu + ((u >> 16) & 1u)) >> 16);
}

// ---------------- kernel 0: pack W1/W2 into bf16 MFMA fragment order ------
// Because A- and B-fragments of mfma_f32_16x16x32_bf16 share the same
// lane->element map (16-dim on lane&15, K on quad*8+j), this pack serves as
// B-frag of W (h@W) AND as A-frag of W^T (swapped mfma).
__global__ __launch_bounds__(256) void pack_kernel(const float* __restrict__ W1,
                                                   const float* __restrict__ W2,
                                                   ushort* __restrict__ wp) {
    int t = blockIdx.x * 256 + threadIdx.x;   // 0..8191
    ushort tmp[8];
    if (t < 4096) {
        int lane = t & 63, nt = (t >> 6) & 3, kt = (t >> 8) & 3, w = (t >> 10) & 3;
        int col = w * 64 + nt * 16 + (lane & 15);
        int kb  = kt * 32 + (lane >> 4) * 8;
        #pragma unroll
        for (int j = 0; j < 8; ++j) tmp[j] = f2b(W1[(kb + j) * 256 + col]);
        uint4 v = make_uint4((unsigned)tmp[0] | ((unsigned)tmp[1] << 16),
                             (unsigned)tmp[2] | ((unsigned)tmp[3] << 16),
                             (unsigned)tmp[4] | ((unsigned)tmp[5] << 16),
                             (unsigned)tmp[6] | ((unsigned)tmp[7] << 16));
        *(uint4*)(wp + t * 8) = v;
    } else {
        int t2 = t - 4096;
        int lane = t2 & 63, nt = (t2 >> 6) & 1, kt = (t2 >> 7) & 7, w = (t2 >> 10) & 3;
        int col = w * 32 + nt * 16 + (lane & 15);
        int kb  = kt * 32 + (lane >> 4) * 8;
        #pragma unroll
        for (int j = 0; j < 8; ++j) tmp[j] = f2b(W2[(kb + j) * 128 + col]);
        uint4 v = make_uint4((unsigned)tmp[0] | ((unsigned)tmp[1] << 16),
                             (unsigned)tmp[2] | ((unsigned)tmp[3] << 16),
                             (unsigned)tmp[4] | ((unsigned)tmp[5] << 16),
                             (unsigned)tmp[6] | ((unsigned)tmp[7] << 16));
        *(uint4*)(wp + 32768 + t2 * 8) = v;
    }
}

// ---------------- fused kernel: MLP (MFMA) + x-copy + edges/attrs/events ---
// Blocks [0,4096): MLP (also writes through its level-3 x rows).
// Blocks [4096,5888): copy of x rows [0,7E). Rest: aux.
#define HP1 136   // h tile row pitch (128 + 8 pad), bf16 elems; 272 B
#define HP2 264   // hidden tile row pitch (256 + 8), 528 B
__global__ __launch_bounds__(256, 2) void fused_kernel(const float* __restrict__ x,
                                                       const float* __restrict__ gf,
                                                       const ushort* __restrict__ wpack,
                                                       const float* __restrict__ b1,
                                                       const float* __restrict__ b2,
                                                       const int* __restrict__ ei,
                                                       const int* __restrict__ ea,
                                                       const int* __restrict__ ev,
                                                       float* __restrict__ out) {
    __shared__ ushort hsh[64 * HP1];
    __shared__ ushort hid[64 * HP2];
    const int bid = blockIdx.x;
    const int tid = threadIdx.x;

    if (bid < MLP_BLOCKS) {
        const int wave = tid >> 6, lane = tid & 63;
        const int quad = lane >> 4, l16 = lane & 15;
        const int row0 = bid * 64;

        // ---- preload W1 fragments (A-frag of W1^T) ----
        short8 w1f[4][4];   // [kt][nt]
        {
            const ushort* wp1 = wpack + wave * 8192;
            #pragma unroll
            for (int kt = 0; kt < 4; ++kt)
                #pragma unroll
                for (int nt = 0; nt < 4; ++nt)
                    w1f[kt][nt] = *(const short8*)(wp1 + (kt * 4 + nt) * 512 + lane * 8);
        }

        // ---- stage h = [x_row | gf[e]] as bf16: 64 rows x 128 ----
        // x-half threads also write the row through to out (the x-copy of the
        // level-3 slice), removing the duplicate HBM read by the copy path.
        #pragma unroll
        for (int it = 0; it < 4; ++it) {
            int q  = tid + 256 * it;      // 0..1023
            int r  = q >> 4;              // row 0..63
            int cc = q & 15;              // 8-elem chunk 0..15
            int rg = row0 + r;
            const float* src = (cc < 8) ? (x + (OFF3 + rg) * 64 + cc * 8)
                                        : (gf + (rg & (E - 1)) * 64 + (cc - 8) * 8);
            float4 a  = *(const float4*)src;
            float4 bv = *(const float4*)(src + 4);
            if (cc < 8) {
                float* dst = out + (size_t)(OFF3 + rg) * 64 + cc * 8;
                *(float4*)dst       = a;
                *(float4*)(dst + 4) = bv;
            }
            uint4 v = make_uint4((unsigned)f2b(a.x)  | ((unsigned)f2b(a.y)  << 16),
                                 (unsigned)f2b(a.z)  | ((unsigned)f2b(a.w)  << 16),
                                 (unsigned)f2b(bv.x) | ((unsigned)f2b(bv.y) << 16),
                                 (unsigned)f2b(bv.z) | ((unsigned)f2b(bv.w) << 16));
            *(uint4*)&hsh[r * HP1 + cc * 8] = v;
        }
        __syncthreads();

        // ---- GEMM1 (swapped): lane holds fixed m=mt*16+l16, 4 consecutive
        //      n = wave*64+nt*16+quad*4+i -> packed b64 LDS writes.
        floatx4 acc1[4][4];   // [mt][nt]
        #pragma unroll
        for (int mt = 0; mt < 4; ++mt)
            #pragma unroll
            for (int nt = 0; nt < 4; ++nt)
                acc1[mt][nt] = (floatx4){0.f, 0.f, 0.f, 0.f};
        #pragma unroll
        for (int mt = 0; mt < 4; ++mt) {
            short8 af[4];
            #pragma unroll
            for (int kt = 0; kt < 4; ++kt)
                af[kt] = *(const short8*)&hsh[(mt * 16 + l16) * HP1 + kt * 32 + quad * 8];
            #pragma unroll
            for (int nt = 0; nt < 4; ++nt)
                #pragma unroll
                for (int kt = 0; kt < 4; ++kt)
                    acc1[mt][nt] = __builtin_amdgcn_mfma_f32_16x16x32_bf16(
                        w1f[kt][nt], af[kt], acc1[mt][nt], 0, 0, 0);
        }

        // ---- preload W2 fragments (deferred to cut peak VGPR) ----
        short8 w2f[8][2];   // [kt][nt]
        {
            const ushort* wp2 = wpack + 32768 + wave * 8192;
            #pragma unroll
            for (int kt = 0; kt < 8; ++kt)
                #pragma unroll
                for (int nt = 0; nt < 2; ++nt)
                    w2f[kt][nt] = *(const short8*)(wp2 + (kt * 2 + nt) * 512 + lane * 8);
        }

        // ---- epilogue 1: bias+relu -> bf16, packed 8B LDS writes ----
        #pragma unroll
        for (int nt = 0; nt < 4; ++nt) {
            float4 bb = *(const float4*)(b1 + wave * 64 + nt * 16 + quad * 4);
            #pragma unroll
            for (int mt = 0; mt < 4; ++mt) {
                int m = mt * 16 + l16;
                unsigned lo = (unsigned)f2b(fmaxf(acc1[mt][nt][0] + bb.x, 0.f)) |
                              ((unsigned)f2b(fmaxf(acc1[mt][nt][1] + bb.y, 0.f)) << 16);
                unsigned hi = (unsigned)f2b(fmaxf(acc1[mt][nt][2] + bb.z, 0.f)) |
                              ((unsigned)f2b(fmaxf(acc1[mt][nt][3] + bb.w, 0.f)) << 16);
                uint2 v = make_uint2(lo, hi);
                *(uint2*)&hid[m * HP2 + wave * 64 + nt * 16 + quad * 4] = v;
            }
        }
        __syncthreads();

        // ---- GEMM2 (swapped): lane holds fixed m, 4 consecutive out cols ----
        floatx4 acc2[4][2];
        #pragma unroll
        for (int mt = 0; mt < 4; ++mt)
            #pragma unroll
            for (int nt = 0; nt < 2; ++nt)
                acc2[mt][nt] = (floatx4){0.f, 0.f, 0.f, 0.f};
        #pragma unroll
        for (int mt = 0; mt < 4; ++mt) {
            short8 hf[8];
            #pragma unroll
            for (int kt = 0; kt < 8; ++kt)
                hf[kt] = *(const short8*)&hid[(mt * 16 + l16) * HP2 + kt * 32 + quad * 8];
            #pragma unroll
            for (int nt = 0; nt < 2; ++nt)
                #pragma unroll
                for (int kt = 0; kt < 8; ++kt)
                    acc2[mt][nt] = __builtin_amdgcn_mfma_f32_16x16x32_bf16(
                        w2f[kt][nt], hf[kt], acc2[mt][nt], 0, 0, 0);
        }
        #pragma unroll
        for (int nt = 0; nt < 2; ++nt) {
            float4 bb = *(const float4*)(b2 + wave * 32 + nt * 16 + quad * 4);
            #pragma unroll
            for (int mt = 0; mt < 4; ++mt) {
                int m = mt * 16 + l16;
                float4 v = make_float4(acc2[mt][nt][0] + bb.x, acc2[mt][nt][1] + bb.y,
                                       acc2[mt][nt][2] + bb.z, acc2[mt][nt][3] + bb.w);
                *(float4*)(out + N0 * F + (size_t)(row0 + m) * 128 + wave * 32 + nt * 16 + quad * 4) = v;
            }
        }
    } else if (bid < MLP_BLOCKS + COPY_BLOCKS) {
        // ---- copy x rows [0, 7E): 2048 float4 per block, 8 per thread ----
        int cb = bid - MLP_BLOCKS;
        const float4* src = (const float4*)x;
        float4* dst = (float4*)out;
        int base = cb * 2048 + tid;
        float4 v[8];
        #pragma unroll
        for (int j = 0; j < 8; ++j) v[j] = src[base + j * 256];
        #pragma unroll
        for (int j = 0; j < 8; ++j) dst[base + j * 256] = v[j];
    } else {
        // ---- edges / attrs / events (4-wide), grid-strided ----
        int ab = bid - MLP_BLOCKS - COPY_BLOCKS;
        #pragma unroll
        for (int it = 0; it < 4; ++it) {
            int i4 = ab * 256 + tid + it * AUX_STRIDE;
            if (i4 < EC1 / 4) {
                int i = i4 * 4;
                float4 sf, tf, af;
                if (i < EC0) {
                    int4 sv = ((const int4*)ei)[i4];
                    int4 tv = ((const int4*)(ei + EC0))[i4];
                    int4 av = ((const int4*)ea)[i4];
                    sf = make_float4((float)sv.x, (float)sv.y, (float)sv.z, (float)sv.w);
                    tf = make_float4((float)tv.x, (float)tv.y, (float)tv.z, (float)tv.w);
                    af = make_float4((float)av.x, (float)av.y, (float)av.z, (float)av.w);
                } else {
                    float s[4], t[4], a[4];
                    #pragma unroll
                    for (int q = 0; q < 4; ++q) {
                        int k = i + q - EC0;
                        int p = k >> 18;
                        int r = k & (262144 - 1);
                        int d = r >> 16;
                        int j = r & (BE - 1);
                        s[q] = (float)(E * (((8 >> d) - 1) + (p >> d)) + (j & (E - 1)));
                        t[q] = (float)(N0 + p * BE + j);
                        a[q] = (float)(d + 1);
                    }
                    sf = make_float4(s[0], s[1], s[2], s[3]);
                    tf = make_float4(t[0], t[1], t[2], t[3]);
                    af = make_float4(a[0], a[1], a[2], a[3]);
                }
                ((float4*)(out + OXE))[i4]       = sf;
                ((float4*)(out + OXE + EC1))[i4] = tf;
                ((float4*)(out + OEA))[i4]       = af;
            }
            if (i4 < NEV / 4) {
                int i = i4 * 4;
                float4 v;
                if (i < N0) {
                    int4 e = ((const int4*)ev)[i4];
                    v = make_float4((float)e.x, (float)e.y, (float)e.z, (float)e.w);
                } else {
                    int base = (i - N0) & (E - 1);
                    v = make_float4((float)base, (float)(base + 1), (float)(base + 2), (float)(base + 3));
                }
                ((float4*)(out + OEV))[i4] = v;
            }
        }
    }
}

// ---------------- launcher ----------------
extern "C" void kernel_launch(void* const* d_in, const int* in_sizes, int n_in,
                              void* d_out, int out_size, void* d_ws, size_t ws_size,
                              hipStream_t stream) {
    const float* x  = (const float*)d_in[0];
    const int*   ei = (const int*)d_in[1];
    const int*   ea = (const int*)d_in[2];
    const int*   ev = (const int*)d_in[3];
    const float* gf = (const float*)d_in[4];
    const float* W1 = (const float*)d_in[5];
    const float* W2 = (const float*)d_in[7];
    const float* b1 = (const float*)d_in[6];
    const float* b2 = (const float*)d_in[8];
    float* out = (float*)d_out;
    ushort* wpack = (ushort*)d_ws;   // 65536 bf16 = 128 KB

    pack_kernel<<<32, 256, 0, stream>>>(W1, W2, wpack);
    fused_kernel<<<TOT_BLOCKS, 256, 0, stream>>>(x, gf, wpack, b1, b2,
                                                 ei, ea, ev, out);
}